// Round 6
// baseline (261.874 us; speedup 1.0000x reference)
//
#include <hip/hip_runtime.h>
#include <hip/hip_bf16.h>
#include <math.h>

#define THREADS 256
typedef unsigned short ushortT;
typedef __attribute__((ext_vector_type(8))) short bf16x8;   // 8 bf16 = 4 VGPRs
typedef __attribute__((ext_vector_type(4))) float f32x4;

__device__ __forceinline__ void async16(const ushortT* g, ushortT* l) {
  __builtin_amdgcn_global_load_lds(
      (const __attribute__((address_space(1))) unsigned int*)g,
      (__attribute__((address_space(3))) unsigned int*)l, 16, 0, 0);
}

__device__ __forceinline__ ushortT f2bf(float f) {
  __hip_bfloat16 h = __float2bfloat16(f);
  return *reinterpret_cast<ushortT*>(&h);
}

// ---------------------------------------------------------------------------
// Kernel A: fused L2-norm + bf16 convert. One block per row (256 thr x float4).
// ---------------------------------------------------------------------------
__global__ __launch_bounds__(THREADS) void k_prep(const float* __restrict__ x,
                                                  ushortT* __restrict__ xn, int D) {
  __shared__ float red[4];
  const int row = blockIdx.x;
  const int tid = threadIdx.x;
  const int gid = row * (D / 4) + tid;
  const float4 v = reinterpret_cast<const float4*>(x)[gid];
  float s = v.x * v.x + v.y * v.y + v.z * v.z + v.w * v.w;
  #pragma unroll
  for (int off = 32; off; off >>= 1) s += __shfl_xor(s, off);
  if ((tid & 63) == 0) red[tid >> 6] = s;
  __syncthreads();
  const float tot = red[0] + red[1] + red[2] + red[3];
  const float rn = 1.0f / fmaxf(sqrtf(tot), 1e-12f);
  ushort4 o;
  o.x = f2bf(v.x * rn); o.y = f2bf(v.y * rn);
  o.z = f2bf(v.z * rn); o.w = f2bf(v.w * rn);
  reinterpret_cast<ushort4*>(xn)[gid] = o;
}

// ---------------------------------------------------------------------------
// Kernel B: triangular 128x128 bf16 MFMA tiles, double-buffered LDS staging,
// XCD-PINNED 8x8 SUPERTILE SWIZZLE for L2 locality:
//   nb=64 tile-blocks/dim -> snb=8 supertiles/dim -> 36 supertiles.
//   Global tile order: for x in 0..7 (XCD via blockIdx%8 round-robin), for
//   s in {x, x+8, x+16, ...}: tiles of supertile s. One supertile's A+B
//   panels = 2 x 4 MB ~= one XCD's L2, so co-resident blocks on an XCD
//   share a small working set instead of thrashing over ~50 MB.
// Epilogue: circle-loss dual-orientation partials; the two 64-col halves of
// each row are merged in LDS, then written coalesced to
// partial[cb * B + row] = {m, sp, sn, 0} (one float4 per (col-block,row)).
// ---------------------------------------------------------------------------
__global__ __launch_bounds__(THREADS, 4) void k_main_mfma(const ushortT* __restrict__ xn,
                                                          const int* __restrict__ tgt,
                                                          float4* __restrict__ partial,
                                                          int D, int B) {
  __shared__ ushortT Asm[2][128 * 32];  // 2 x 8 KB
  __shared__ ushortT Bsm[2][128 * 32];  // 2 x 8 KB

  const int tid = threadIdx.x;
  const int lane = tid & 63;
  const int w = tid >> 6;

  // --- supertile decode (wave-uniform scalar; nb=64, snb=8 hardcoded)
  const int b = blockIdx.x;
  int base = 0, SI = 0, SJ = 0, found = 0;
  for (int x = 0; x < 8 && !found; ++x) {
    for (int ss = x; ss < 36; ss += 8) {
      int si = 0, rem = ss;
      while (rem >= 8 - si) { rem -= 8 - si; ++si; }
      const int sj = si + rem;
      const int size = (si == sj) ? 36 : 64;
      if (b < base + size) { SI = si; SJ = sj; found = 1; break; }
      base += size;
    }
  }
  const int l = b - base;
  int li, lj;
  if (SI == SJ) {
    int t = l, row = 0;
    while (t >= 8 - row) { t -= 8 - row; ++row; }
    li = row; lj = row + t;
  } else {
    li = l >> 3; lj = l & 7;
  }
  const int bi = SI * 8 + li;
  const int bj = SJ * 8 + lj;
  const bool isdiag = (bi == bj);

  const int i0 = bi * 128, j0 = bj * 128;
  const int wr = (w >> 1) * 64, wc = (w & 1) * 64;

  // --- staging: lane fetches (row = lane&15, chunk = lane>>4) of its group
  const int sr = lane & 15, sc = lane >> 4;
  const ushortT* gA0 = xn + (size_t)(i0 + w * 16 + sr) * D + sc * 8;
  const ushortT* gA1 = gA0 + (size_t)64 * D;
  const ushortT* gB0 = xn + (size_t)(j0 + w * 16 + sr) * D + sc * 8;
  const ushortT* gB1 = gB0 + (size_t)64 * D;
  const int lo0 = w * 512;        // ushort offset within a buffer
  const int lo1 = (w + 4) * 512;

  const int aoff = ((w >> 1) * 4) * 512 + lane * 8;   // ushort index
  const int boff = ((w & 1) * 4) * 512 + lane * 8;

  f32x4 acc[4][4];
  #pragma unroll
  for (int mt = 0; mt < 4; ++mt)
    #pragma unroll
    for (int nt = 0; nt < 4; ++nt)
      acc[mt][nt] = (f32x4){0.f, 0.f, 0.f, 0.f};

  // prologue: stage k=0 into buffer 0
  async16(gA0, &Asm[0][lo0]);
  async16(gA1, &Asm[0][lo1]);
  if (!isdiag) {
    async16(gB0, &Bsm[0][lo0]);
    async16(gB1, &Bsm[0][lo1]);
  }
  __syncthreads();

  const int kiters = D / 32;
  for (int kk = 0; kk < kiters; ++kk) {
    const int cur = kk & 1;
    if (kk + 1 < kiters) {   // stage next into other buffer BEFORE compute
      const size_t ko = (size_t)(kk + 1) * 32;
      async16(gA0 + ko, &Asm[cur ^ 1][lo0]);
      async16(gA1 + ko, &Asm[cur ^ 1][lo1]);
      if (!isdiag) {
        async16(gB0 + ko, &Bsm[cur ^ 1][lo0]);
        async16(gB1 + ko, &Bsm[cur ^ 1][lo1]);
      }
    }
    const ushortT* Ab = &Asm[cur][0];
    const ushortT* Bb = isdiag ? &Asm[cur][0] : &Bsm[cur][0];
    bf16x8 afr[4], bfr[4];
    #pragma unroll
    for (int mt = 0; mt < 4; ++mt)
      afr[mt] = *reinterpret_cast<const bf16x8*>(&Ab[aoff + mt * 512]);
    #pragma unroll
    for (int nt = 0; nt < 4; ++nt)
      bfr[nt] = *reinterpret_cast<const bf16x8*>(&Bb[boff + nt * 512]);
    #pragma unroll
    for (int mt = 0; mt < 4; ++mt)
      #pragma unroll
      for (int nt = 0; nt < 4; ++nt)
        acc[mt][nt] = __builtin_amdgcn_mfma_f32_16x16x32_bf16(afr[mt], bfr[nt], acc[mt][nt], 0, 0, 0);
    __syncthreads();   // seals buf[cur] reads; drains the kk+1 prefetch
  }

  // --- epilogue. C/D layout: col = lane&15, row = (lane>>4)*4 + reg
  const int q = lane >> 4, c = lane & 15;
  int tj[4];
  #pragma unroll
  for (int nt = 0; nt < 4; ++nt) tj[nt] = tgt[j0 + wc + nt * 16 + c];
  int tir[16];
  #pragma unroll
  for (int mt = 0; mt < 4; ++mt) {
    const int4 t4 = *reinterpret_cast<const int4*>(tgt + i0 + wr + mt * 16 + q * 4);
    tir[mt * 4 + 0] = t4.x; tir[mt * 4 + 1] = t4.y;
    tir[mt * 4 + 2] = t4.z; tir[mt * 4 + 3] = t4.w;
  }

  // LDS stash for half-merging (reuse Asm; K-loop's final barrier sealed it)
  float4* eo1 = reinterpret_cast<float4*>(&Asm[0][0]);     // [128][2]
  float4* eo2 = reinterpret_cast<float4*>(&Asm[0][2048]);  // [128][2]

  // orientation 1: rows of bi block, cols of bj block
  #pragma unroll
  for (int mt = 0; mt < 4; ++mt) {
    #pragma unroll
    for (int reg = 0; reg < 4; ++reg) {
      const int il = wr + mt * 16 + q * 4 + reg;
      const int i = i0 + il;
      const int ti = tir[mt * 4 + reg];
      float m = -1e30f, sn = 0.f;
      float sel[4];
      #pragma unroll
      for (int nt = 0; nt < 4; ++nt) {
        const float s = acc[mt][nt][reg];
        const int j = j0 + wc + nt * 16 + c;
        const bool same = (tj[nt] == ti);
        const bool vpos = same && (j != i);
        const float lp = (fminf(s, 1.25f) - 1.25f) * fmaf(s, 64.f, -48.f);
        const float sv = vpos ? lp : -2e30f;
        sel[nt] = sv;
        m = fmaxf(m, sv);
        const float ln = (fmaxf(s, -0.25f) + 0.25f) * fmaf(s, 64.f, -16.f);
        const float en = __expf(ln);
        sn += same ? 0.f : en;
      }
      #pragma unroll
      for (int off = 1; off < 16; off <<= 1) m = fmaxf(m, __shfl_xor(m, off));
      float sp = 0.f;
      #pragma unroll
      for (int nt = 0; nt < 4; ++nt) sp += __expf(sel[nt] - m);
      #pragma unroll
      for (int off = 1; off < 16; off <<= 1) {
        sp += __shfl_xor(sp, off);
        sn += __shfl_xor(sn, off);
      }
      if (c == 0) {
        float4 o; o.x = m; o.y = sp; o.z = sn; o.w = 0.f;
        eo1[il * 2 + (w & 1)] = o;
      }
    }
  }

  // orientation 2: rows of bj block, cols of bi block (off-diagonal only)
  if (!isdiag) {
    #pragma unroll
    for (int nt = 0; nt < 4; ++nt) {
      const int jt = tj[nt];
      float m = -1e30f, sn = 0.f;
      float sel[16];
      #pragma unroll
      for (int mt = 0; mt < 4; ++mt) {
        #pragma unroll
        for (int reg = 0; reg < 4; ++reg) {
          const float s = acc[mt][nt][reg];
          const bool same = (tir[mt * 4 + reg] == jt);  // j != i off-diagonal
          const float lp = (fminf(s, 1.25f) - 1.25f) * fmaf(s, 64.f, -48.f);
          const float sv = same ? lp : -2e30f;
          sel[mt * 4 + reg] = sv;
          m = fmaxf(m, sv);
          const float ln = (fmaxf(s, -0.25f) + 0.25f) * fmaf(s, 64.f, -16.f);
          const float en = __expf(ln);
          sn += same ? 0.f : en;
        }
      }
      m = fmaxf(m, __shfl_xor(m, 16));
      m = fmaxf(m, __shfl_xor(m, 32));
      float sp = 0.f;
      #pragma unroll
      for (int k = 0; k < 16; ++k) sp += __expf(sel[k] - m);
      sp += __shfl_xor(sp, 16); sp += __shfl_xor(sp, 32);
      sn += __shfl_xor(sn, 16); sn += __shfl_xor(sn, 32);
      if (lane < 16) {
        float4 o; o.x = m; o.y = sp; o.z = sn; o.w = 0.f;
        eo2[(wc + nt * 16 + lane) * 2 + (w >> 1)] = o;
      }
    }
  }

  __syncthreads();

  // merge halves and write coalesced: partial[cb * B + row]
  if (tid < 128) {
    const float4 a = eo1[tid * 2], bb = eo1[tid * 2 + 1];
    const float m = fmaxf(a.x, bb.x);
    float4 o;
    o.x = m;
    o.y = a.y * __expf(a.x - m) + bb.y * __expf(bb.x - m);
    o.z = a.z + bb.z;
    o.w = 0.f;
    partial[(size_t)bj * B + i0 + tid] = o;
  } else if (!isdiag) {
    const int t = tid - 128;
    const float4 a = eo2[t * 2], bb = eo2[t * 2 + 1];
    const float m = fmaxf(a.x, bb.x);
    float4 o;
    o.x = m;
    o.y = a.y * __expf(a.x - m) + bb.y * __expf(bb.x - m);
    o.z = a.z + bb.z;
    o.w = 0.f;
    partial[(size_t)bi * B + j0 + t] = o;
  }
}

// ---------------------------------------------------------------------------
// Kernel C: fold 64 per-colblock partials per row -> row loss. One wave/row.
// partial[cb * B + row], cb in [0,64).
// ---------------------------------------------------------------------------
__global__ __launch_bounds__(THREADS) void k_reduce(const float4* __restrict__ partial,
                                                    float* __restrict__ row_loss,
                                                    int B) {
  const int lane = threadIdx.x & 63;
  const int row = blockIdx.x * 4 + (threadIdx.x >> 6);
  const float4 p = partial[(size_t)lane * B + row];
  float mp = p.x, sp = p.y, sn = p.z;
  #pragma unroll
  for (int off = 1; off < 64; off <<= 1) {
    const float m2 = __shfl_xor(mp, off), s2 = __shfl_xor(sp, off);
    const float nm = fmaxf(mp, m2);
    sp = sp * __expf(mp - nm) + s2 * __expf(m2 - nm);
    mp = nm;
    sn += __shfl_xor(sn, off);
  }
  if (lane == 0) {
    float loss = -1.0f;
    if (sp > 0.f && sn > 0.f) {
      const float z = mp + logf(sp) + logf(sn);
      loss = (z > 0.f) ? (z + log1pf(__expf(-z))) : log1pf(__expf(z));
    }
    row_loss[row] = loss;
  }
}

// ---------------------------------------------------------------------------
// Kernel D: masked mean over rows. One block.
// ---------------------------------------------------------------------------
__global__ __launch_bounds__(THREADS) void k_final(const float* __restrict__ row_loss,
                                                   float* __restrict__ out, int B) {
  __shared__ float ssum[4];
  __shared__ float scnt[4];
  const int tid = threadIdx.x;
  float sum = 0.f, cnt = 0.f;
  for (int i = tid; i < B; i += THREADS) {
    const float l = row_loss[i];
    if (l >= 0.f) { sum += l; cnt += 1.f; }
  }
  #pragma unroll
  for (int off = 32; off; off >>= 1) {
    sum += __shfl_xor(sum, off);
    cnt += __shfl_xor(cnt, off);
  }
  if ((tid & 63) == 0) { ssum[tid >> 6] = sum; scnt[tid >> 6] = cnt; }
  __syncthreads();
  if (tid == 0) {
    float ts = 0.f, tc = 0.f;
    #pragma unroll
    for (int w = 0; w < 4; ++w) { ts += ssum[w]; tc += scnt[w]; }
    out[0] = ts / fmaxf(tc, 1.f);
  }
}

// ---------------------------------------------------------------------------
extern "C" void kernel_launch(void* const* d_in, const int* in_sizes, int n_in,
                              void* d_out, int out_size, void* d_ws, size_t ws_size,
                              hipStream_t stream) {
  const float* x = (const float*)d_in[0];
  const int* tgt = (const int*)d_in[1];
  float* out = (float*)d_out;
  const int B = in_sizes[1];
  const int D = in_sizes[0] / B;
  const int nb = B / 128;   // 64

  ushortT* xn = (ushortT*)d_ws;                                   // B*D bf16 (16 MB)
  float4* partial = (float4*)((char*)d_ws + (size_t)B * D * 2);   // nb*B float4 (8.4 MB)
  float* row_loss = (float*)((char*)d_ws + (size_t)B * D * 2 + (size_t)nb * B * 16);

  k_prep<<<B, THREADS, 0, stream>>>(x, xn, D);
  k_main_mfma<<<nb * (nb + 1) / 2, THREADS, 0, stream>>>(xn, tgt, partial, D, B);
  k_reduce<<<B / 4, THREADS, 0, stream>>>(partial, row_loss, B);
  k_final<<<1, THREADS, 0, stream>>>(row_loss, out, B);
}